// Round 2
// baseline (957.450 us; speedup 1.0000x reference)
//
#include <hip/hip_runtime.h>
#include <hip/hip_bf16.h>
#include <stdint.h>

typedef __bf16 bf16x8 __attribute__((ext_vector_type(8)));
typedef float f32x4 __attribute__((ext_vector_type(4)));

#define SOFTMAX_SCALE 0.08838834764831845f
#define LOG2E 1.44269504088896f

// load 8 contiguous elements as bf16x8, converting if the source is fp32
__device__ __forceinline__ bf16x8 load8_cvt(const __hip_bfloat16* p) {
  return *(const bf16x8*)p;
}
__device__ __forceinline__ bf16x8 load8_cvt(const float* p) {
  float4 a = *(const float4*)p;
  float4 b = *(const float4*)(p + 4);
  bf16x8 r;
  r[0] = (__bf16)a.x; r[1] = (__bf16)a.y; r[2] = (__bf16)a.z; r[3] = (__bf16)a.w;
  r[4] = (__bf16)b.x; r[5] = (__bf16)b.y; r[6] = (__bf16)b.z; r[7] = (__bf16)b.w;
  return r;
}

// ---------------------------------------------------------------------------
// GEMM core: C = A * B^T, A[M][K], B[N][K] row-major (fp32 or bf16 source),
// fp32 accum. Block = 256 threads (4 waves, 2x2 of 64x64), tile 128x128, BK=64.
// LDS bf16, XOR-swizzle: 16B chunk index ^= (row & 7).
// ---------------------------------------------------------------------------
template <typename TA, typename TB>
__device__ __forceinline__ void gemm_bt_loop(
    const TA* __restrict__ A,
    const TB* __restrict__ B,
    int K, int m0, int n0,
    __hip_bfloat16* As, __hip_bfloat16* Bs,
    f32x4 acc[4][4])
{
  const int t = threadIdx.x;
  const int w = t >> 6, lane = t & 63;
  const int wm = (w >> 1) * 64, wn = (w & 1) * 64;
  const int l16 = lane & 15, quad = lane >> 4;

  for (int k0 = 0; k0 < K; k0 += 64) {
    #pragma unroll
    for (int i = 0; i < 4; ++i) {
      int idx = i * 256 + t;          // 0..1023 chunk index (8 bf16 per chunk)
      int row = idx >> 3, ch = idx & 7;
      int sw = (ch ^ (row & 7)) * 8;
      *(bf16x8*)(As + row * 64 + sw) =
          load8_cvt(A + (int64_t)(m0 + row) * K + k0 + ch * 8);
      *(bf16x8*)(Bs + row * 64 + sw) =
          load8_cvt(B + (int64_t)(n0 + row) * K + k0 + ch * 8);
    }
    __syncthreads();
    #pragma unroll
    for (int ks = 0; ks < 2; ++ks) {
      bf16x8 af[4], bfr[4];
      #pragma unroll
      for (int mt = 0; mt < 4; ++mt) {
        int row = wm + mt * 16 + l16;
        int ch = ks * 4 + quad;
        af[mt] = *(const bf16x8*)(As + row * 64 + ((ch ^ (row & 7)) * 8));
      }
      #pragma unroll
      for (int nt = 0; nt < 4; ++nt) {
        int row = wn + nt * 16 + l16;
        int ch = ks * 4 + quad;
        bfr[nt] = *(const bf16x8*)(Bs + row * 64 + ((ch ^ (row & 7)) * 8));
      }
      #pragma unroll
      for (int mt = 0; mt < 4; ++mt)
        #pragma unroll
        for (int nt = 0; nt < 4; ++nt)
          acc[mt][nt] = __builtin_amdgcn_mfma_f32_16x16x32_bf16(
              af[mt], bfr[nt], acc[mt][nt], 0, 0, 0);
    }
    __syncthreads();
  }
}

// ---------------------------------------------------------------------------
// Kernel 1: QKV projection. A=hidden fp32 [4096][2048], W=Wqkv fp32 [6144][2048].
// Epilogue: clamp +-8, scatter to q/k/v [32 bh][2048 s][128 d] bf16.
// ---------------------------------------------------------------------------
__global__ __launch_bounds__(256) void qkv_gemm(
    const float* __restrict__ A,
    const float* __restrict__ W,
    __hip_bfloat16* __restrict__ qb,
    __hip_bfloat16* __restrict__ kb,
    __hip_bfloat16* __restrict__ vb)
{
  __shared__ __align__(16) __hip_bfloat16 As[128 * 64];
  __shared__ __align__(16) __hip_bfloat16 Bs[128 * 64];
  const f32x4 z4 = {0.f, 0.f, 0.f, 0.f};
  f32x4 acc[4][4];
  #pragma unroll
  for (int mt = 0; mt < 4; ++mt)
    #pragma unroll
    for (int nt = 0; nt < 4; ++nt) acc[mt][nt] = z4;

  const int K = 2048;
  const int n0 = blockIdx.x * 128, m0 = blockIdx.y * 128;
  gemm_bt_loop(A, W, K, m0, n0, As, Bs, acc);

  const int t = threadIdx.x;
  const int w = t >> 6, lane = t & 63;
  const int wm = (w >> 1) * 64, wn = (w & 1) * 64;
  const int l16 = lane & 15, quad = lane >> 4;
  __hip_bfloat16* bufs[3] = {qb, kb, vb};
  #pragma unroll
  for (int nt = 0; nt < 4; ++nt) {
    int gn = n0 + wn + nt * 16 + l16;
    int which = gn >> 11;          // 0=q 1=k 2=v
    int hc = gn & 2047;
    int head = hc >> 7, d = hc & 127;
    __hip_bfloat16* dst = bufs[which];
    #pragma unroll
    for (int mt = 0; mt < 4; ++mt) {
      #pragma unroll
      for (int r = 0; r < 4; ++r) {
        int gm = m0 + wm + mt * 16 + quad * 4 + r;
        int bb = gm >> 11, s = gm & 2047;
        float val = acc[mt][nt][r];
        val = fminf(8.f, fmaxf(-8.f, val));
        dst[(((int64_t)(bb * 16 + head) * 2048 + s) << 7) + d] =
            __float2bfloat16(val);
      }
    }
  }
}

// ---------------------------------------------------------------------------
// Kernel 2: V transpose per head: V [bh][2048 s][128 d] -> Vt [bh][128 d][2048 s]
// ---------------------------------------------------------------------------
__global__ __launch_bounds__(256) void transpose_v(
    const __hip_bfloat16* __restrict__ V,
    __hip_bfloat16* __restrict__ Vt)
{
  __shared__ __hip_bfloat16 tile[64][68];
  const int bh = blockIdx.z;
  const int s0 = blockIdx.x * 64;
  const int d0 = blockIdx.y * 64;
  const int t = threadIdx.x;
  const int c = t & 63, rq = t >> 6;
  const __hip_bfloat16* Vp = V + (int64_t)bh * 2048 * 128;
  #pragma unroll
  for (int j = 0; j < 16; ++j) {
    int r = rq * 16 + j;
    tile[r][c] = Vp[(int64_t)(s0 + r) * 128 + d0 + c];
  }
  __syncthreads();
  __hip_bfloat16* Vo = Vt + (int64_t)bh * 128 * 2048;
  #pragma unroll
  for (int j = 0; j < 16; ++j) {
    int dd = rq * 16 + j;
    Vo[(int64_t)(d0 + dd) * 2048 + s0 + c] = tile[c][dd];
  }
}

// ---------------------------------------------------------------------------
// Kernel 3: flash attention. One block per (bh, 128-row q-tile).
// 4 waves x 32 q-rows. K tile [128 kpos][128 hd] and Vt tile [128 hd][128 kpos]
// staged in LDS with chunk^(row&15) swizzle. P reuses the K region.
// bias is fp32 global.
// ---------------------------------------------------------------------------
__global__ __launch_bounds__(256, 1) void attn_kernel(
    const __hip_bfloat16* __restrict__ Q,
    const __hip_bfloat16* __restrict__ Kg,
    const __hip_bfloat16* __restrict__ Vt,
    const float* __restrict__ bias,
    __hip_bfloat16* __restrict__ ctx)
{
  __shared__ __align__(16) __hip_bfloat16 Ks[128 * 128];   // K tile; reused as P
  __shared__ __align__(16) __hip_bfloat16 Vs[128 * 128];   // Vt tile

  const int t = threadIdx.x;
  const int w = t >> 6, lane = t & 63;
  const int l16 = lane & 15, quad = lane >> 4;

  const int bh = blockIdx.y;
  const int h = bh & 15, b = bh >> 4;
  const int qt = 15 - (int)blockIdx.x;       // heavy q-tiles first
  const int q0 = qt * 128;

  bf16x8 qf[2][4];
  {
    const __hip_bfloat16* Qp = Q + ((int64_t)bh * 2048 + q0 + w * 32) * 128;
    #pragma unroll
    for (int mt = 0; mt < 2; ++mt) {
      int row = mt * 16 + l16;
      #pragma unroll
      for (int ks = 0; ks < 4; ++ks)
        qf[mt][ks] = *(const bf16x8*)(Qp + row * 128 + ks * 32 + quad * 8);
    }
  }

  const f32x4 z4 = {0.f, 0.f, 0.f, 0.f};
  f32x4 O[2][8];
  #pragma unroll
  for (int mt = 0; mt < 2; ++mt)
    #pragma unroll
    for (int nt = 0; nt < 8; ++nt) O[mt][nt] = z4;
  float m_r[2][4], l_r[2][4];
  #pragma unroll
  for (int mt = 0; mt < 2; ++mt)
    #pragma unroll
    for (int r = 0; r < 4; ++r) { m_r[mt][r] = -3.0e38f; l_r[mt][r] = 0.f; }

  const __hip_bfloat16* Kbase = Kg + (int64_t)bh * 2048 * 128;
  const __hip_bfloat16* Vbase = Vt + (int64_t)bh * 128 * 2048;
  const float* Bbase = bias + (int64_t)h * 2048 * 2048;

  for (int kt = 0; kt <= qt; ++kt) {
    const __hip_bfloat16* Kp = Kbase + (int64_t)kt * 128 * 128;
    const __hip_bfloat16* Vp = Vbase + kt * 128;
    #pragma unroll
    for (int i = 0; i < 8; ++i) {
      int idx = i * 256 + t;        // 16B-chunk index, 16 chunks per row
      int row = idx >> 4, ch = idx & 15;
      int sw = (ch ^ (row & 15)) * 8;
      *(bf16x8*)(Ks + row * 128 + sw) =
          *(const bf16x8*)(Kp + row * 128 + ch * 8);
      *(bf16x8*)(Vs + row * 128 + sw) =
          *(const bf16x8*)(Vp + (int64_t)row * 2048 + ch * 8);
    }
    __syncthreads();

    // S = Q * K^T
    f32x4 S[2][8];
    #pragma unroll
    for (int mt = 0; mt < 2; ++mt)
      #pragma unroll
      for (int nt = 0; nt < 8; ++nt) S[mt][nt] = z4;
    #pragma unroll
    for (int ks = 0; ks < 4; ++ks) {
      bf16x8 kf[8];
      #pragma unroll
      for (int nt = 0; nt < 8; ++nt) {
        int row = nt * 16 + l16;
        int ch = ks * 4 + quad;
        kf[nt] = *(const bf16x8*)(Ks + row * 128 + ((ch ^ (row & 15)) * 8));
      }
      #pragma unroll
      for (int mt = 0; mt < 2; ++mt)
        #pragma unroll
        for (int nt = 0; nt < 8; ++nt)
          S[mt][nt] = __builtin_amdgcn_mfma_f32_16x16x32_bf16(
              qf[mt][ks], kf[nt], S[mt][nt], 0, 0, 0);
    }

    // scale + bias (fp32) + causal mask (C layout: row=quad*4+r, col=l16)
    const bool diag = (kt == qt);
    #pragma unroll
    for (int mt = 0; mt < 2; ++mt) {
      #pragma unroll
      for (int r = 0; r < 4; ++r) {
        int gq = q0 + w * 32 + mt * 16 + quad * 4 + r;
        const float* brow = Bbase + (int64_t)gq * 2048 + kt * 128;
        #pragma unroll
        for (int nt = 0; nt < 8; ++nt) {
          int ck = nt * 16 + l16;
          float sv = S[mt][nt][r] * SOFTMAX_SCALE + brow[ck];
          if (diag && (kt * 128 + ck > gq)) sv = -3.0e38f;
          S[mt][nt][r] = sv;
        }
      }
    }

    // online softmax: row stats live across each 16-lane group
    #pragma unroll
    for (int mt = 0; mt < 2; ++mt) {
      #pragma unroll
      for (int r = 0; r < 4; ++r) {
        float rm = S[mt][0][r];
        #pragma unroll
        for (int nt = 1; nt < 8; ++nt) rm = fmaxf(rm, S[mt][nt][r]);
        rm = fmaxf(rm, __shfl_xor(rm, 1, 64));
        rm = fmaxf(rm, __shfl_xor(rm, 2, 64));
        rm = fmaxf(rm, __shfl_xor(rm, 4, 64));
        rm = fmaxf(rm, __shfl_xor(rm, 8, 64));
        float mo = m_r[mt][r];
        float mn = fmaxf(mo, rm);
        float alpha = exp2f((mo - mn) * LOG2E);
        float rs = 0.f;
        #pragma unroll
        for (int nt = 0; nt < 8; ++nt) {
          float pv = exp2f((S[mt][nt][r] - mn) * LOG2E);
          S[mt][nt][r] = pv;
          rs += pv;
        }
        rs += __shfl_xor(rs, 1, 64);
        rs += __shfl_xor(rs, 2, 64);
        rs += __shfl_xor(rs, 4, 64);
        rs += __shfl_xor(rs, 8, 64);
        m_r[mt][r] = mn;
        l_r[mt][r] = l_r[mt][r] * alpha + rs;
        #pragma unroll
        for (int nt = 0; nt < 8; ++nt) O[mt][nt][r] *= alpha;
      }
    }
    __syncthreads();    // all waves done reading Ks before P overwrites it

    // P (bf16) -> LDS (K region), [128 qrow][128 kpos], same swizzle
    #pragma unroll
    for (int mt = 0; mt < 2; ++mt)
      #pragma unroll
      for (int r = 0; r < 4; ++r) {
        int prow = w * 32 + mt * 16 + quad * 4 + r;
        #pragma unroll
        for (int nt = 0; nt < 8; ++nt) {
          int col = nt * 16 + l16;
          int addr = prow * 128 + (((col >> 3) ^ (prow & 15)) << 3) + (col & 7);
          Ks[addr] = __float2bfloat16(S[mt][nt][r]);
        }
      }
    __syncthreads();

    // O += P * V : A = P[qrow][kpos], B = Vs[hd][kpos]
    #pragma unroll
    for (int ksp = 0; ksp < 4; ++ksp) {
      bf16x8 pf[2], vf[8];
      #pragma unroll
      for (int mt = 0; mt < 2; ++mt) {
        int row = w * 32 + mt * 16 + l16;
        int ch = ksp * 4 + quad;
        pf[mt] = *(const bf16x8*)(Ks + row * 128 + ((ch ^ (row & 15)) * 8));
      }
      #pragma unroll
      for (int nt = 0; nt < 8; ++nt) {
        int row = nt * 16 + l16;
        int ch = ksp * 4 + quad;
        vf[nt] = *(const bf16x8*)(Vs + row * 128 + ((ch ^ (row & 15)) * 8));
      }
      #pragma unroll
      for (int mt = 0; mt < 2; ++mt)
        #pragma unroll
        for (int nt = 0; nt < 8; ++nt)
          O[mt][nt] = __builtin_amdgcn_mfma_f32_16x16x32_bf16(
              pf[mt], vf[nt], O[mt][nt], 0, 0, 0);
    }
    __syncthreads();    // reads done before next tile staging
  }

  // epilogue: ctx[b*2048 + q][h*128 + d] = O / l   (bf16)
  #pragma unroll
  for (int mt = 0; mt < 2; ++mt) {
    #pragma unroll
    for (int r = 0; r < 4; ++r) {
      int gm = b * 2048 + q0 + w * 32 + mt * 16 + quad * 4 + r;
      float inv = 1.f / l_r[mt][r];
      __hip_bfloat16* crow = ctx + (int64_t)gm * 2048 + h * 128;
      #pragma unroll
      for (int nt = 0; nt < 8; ++nt)
        crow[nt * 16 + l16] = __float2bfloat16(O[mt][nt][r] * inv);
    }
  }
}

// ---------------------------------------------------------------------------
// Kernel 4: output projection. A=ctx bf16 [4096][2048], W=Wout fp32 [2048][2048].
// Output fp32.
// ---------------------------------------------------------------------------
__global__ __launch_bounds__(256) void out_gemm(
    const __hip_bfloat16* __restrict__ A,
    const float* __restrict__ W,
    float* __restrict__ out)
{
  __shared__ __align__(16) __hip_bfloat16 As[128 * 64];
  __shared__ __align__(16) __hip_bfloat16 Bs[128 * 64];
  const f32x4 z4 = {0.f, 0.f, 0.f, 0.f};
  f32x4 acc[4][4];
  #pragma unroll
  for (int mt = 0; mt < 4; ++mt)
    #pragma unroll
    for (int nt = 0; nt < 4; ++nt) acc[mt][nt] = z4;

  const int K = 2048;
  const int n0 = blockIdx.x * 128, m0 = blockIdx.y * 128;
  gemm_bt_loop(A, W, K, m0, n0, As, Bs, acc);

  const int t = threadIdx.x;
  const int w = t >> 6, lane = t & 63;
  const int wm = (w >> 1) * 64, wn = (w & 1) * 64;
  const int l16 = lane & 15, quad = lane >> 4;
  #pragma unroll
  for (int mt = 0; mt < 4; ++mt) {
    #pragma unroll
    for (int r = 0; r < 4; ++r) {
      int gm = m0 + wm + mt * 16 + quad * 4 + r;
      #pragma unroll
      for (int nt = 0; nt < 4; ++nt) {
        int gn = n0 + wn + nt * 16 + l16;
        out[(int64_t)gm * 2048 + gn] = acc[mt][nt][r];
      }
    }
  }
}

// ---------------------------------------------------------------------------
extern "C" void kernel_launch(void* const* d_in, const int* in_sizes, int n_in,
                              void* d_out, int out_size, void* d_ws, size_t ws_size,
                              hipStream_t stream) {
  const float* hs   = (const float*)d_in[0];
  const float* bias = (const float*)d_in[1];
  // d_in[2] = attention_mask: pure causal, applied analytically; never read.
  const float* Wqkv = (const float*)d_in[3];
  const float* Wout = (const float*)d_in[4];
  float* out = (float*)d_out;

  __hip_bfloat16* ws = (__hip_bfloat16*)d_ws;
  const size_t SEG = (size_t)32 * 2048 * 128;   // 8,388,608 elements (16 MB)
  __hip_bfloat16* q   = ws;
  __hip_bfloat16* k   = ws + SEG;
  __hip_bfloat16* v   = ws + 2 * SEG;
  __hip_bfloat16* vt  = ws + 3 * SEG;
  __hip_bfloat16* ctx = ws + 2 * SEG;           // aliases v (dead after transpose)

  qkv_gemm<<<dim3(48, 32), 256, 0, stream>>>(hs, Wqkv, q, k, v);
  transpose_v<<<dim3(32, 2, 32), 256, 0, stream>>>(v, vt);
  attn_kernel<<<dim3(16, 32), 256, 0, stream>>>(q, k, vt, bias, ctx);
  out_gemm<<<dim3(16, 32), 256, 0, stream>>>(ctx, Wout, out);
}

// Round 3
// 898.287 us; speedup vs baseline: 1.0659x; 1.0659x over previous
//
#include <hip/hip_runtime.h>
#include <hip/hip_bf16.h>
#include <stdint.h>

typedef __bf16 bf16x8 __attribute__((ext_vector_type(8)));
typedef float f32x4 __attribute__((ext_vector_type(4)));

#define SOFTMAX_SCALE 0.08838834764831845f
#define LOG2E 1.44269504088896f

// load 8 contiguous elements as bf16x8, converting if the source is fp32
__device__ __forceinline__ bf16x8 load8_cvt(const __hip_bfloat16* p) {
  return *(const bf16x8*)p;
}
__device__ __forceinline__ bf16x8 load8_cvt(const float* p) {
  float4 a = *(const float4*)p;
  float4 b = *(const float4*)(p + 4);
  bf16x8 r;
  r[0] = (__bf16)a.x; r[1] = (__bf16)a.y; r[2] = (__bf16)a.z; r[3] = (__bf16)a.w;
  r[4] = (__bf16)b.x; r[5] = (__bf16)b.y; r[6] = (__bf16)b.z; r[7] = (__bf16)b.w;
  return r;
}

// ---------------------------------------------------------------------------
// fp32 -> bf16 bulk convert (grid-stride, 16B loads / 16B stores)
// ---------------------------------------------------------------------------
__global__ __launch_bounds__(256) void cvt_f32_bf16(
    const float* __restrict__ in, __hip_bfloat16* __restrict__ out, int n8)
{
  int i = blockIdx.x * blockDim.x + threadIdx.x;
  int stride = gridDim.x * blockDim.x;
  for (; i < n8; i += stride)
    *(bf16x8*)(out + (int64_t)i * 8) = load8_cvt(in + (int64_t)i * 8);
}

// ---------------------------------------------------------------------------
// GEMM core: C = A * B^T, A[M][K], B[N][K] row-major (fp32 or bf16 source),
// fp32 accum. Block = 256 threads (4 waves, 2x2 of 64x64), tile 128x128, BK=64.
// LDS bf16, XOR-swizzle: 16B chunk index ^= (row & 7).
// ---------------------------------------------------------------------------
template <typename TA, typename TB>
__device__ __forceinline__ void gemm_bt_loop(
    const TA* __restrict__ A,
    const TB* __restrict__ B,
    int K, int m0, int n0,
    __hip_bfloat16* As, __hip_bfloat16* Bs,
    f32x4 acc[4][4])
{
  const int t = threadIdx.x;
  const int w = t >> 6, lane = t & 63;
  const int wm = (w >> 1) * 64, wn = (w & 1) * 64;
  const int l16 = lane & 15, quad = lane >> 4;

  for (int k0 = 0; k0 < K; k0 += 64) {
    #pragma unroll
    for (int i = 0; i < 4; ++i) {
      int idx = i * 256 + t;          // 0..1023 chunk index (8 bf16 per chunk)
      int row = idx >> 3, ch = idx & 7;
      int sw = (ch ^ (row & 7)) * 8;
      *(bf16x8*)(As + row * 64 + sw) =
          load8_cvt(A + (int64_t)(m0 + row) * K + k0 + ch * 8);
      *(bf16x8*)(Bs + row * 64 + sw) =
          load8_cvt(B + (int64_t)(n0 + row) * K + k0 + ch * 8);
    }
    __syncthreads();
    #pragma unroll
    for (int ks = 0; ks < 2; ++ks) {
      bf16x8 af[4], bfr[4];
      #pragma unroll
      for (int mt = 0; mt < 4; ++mt) {
        int row = wm + mt * 16 + l16;
        int ch = ks * 4 + quad;
        af[mt] = *(const bf16x8*)(As + row * 64 + ((ch ^ (row & 7)) * 8));
      }
      #pragma unroll
      for (int nt = 0; nt < 4; ++nt) {
        int row = wn + nt * 16 + l16;
        int ch = ks * 4 + quad;
        bfr[nt] = *(const bf16x8*)(Bs + row * 64 + ((ch ^ (row & 7)) * 8));
      }
      #pragma unroll
      for (int mt = 0; mt < 4; ++mt)
        #pragma unroll
        for (int nt = 0; nt < 4; ++nt)
          acc[mt][nt] = __builtin_amdgcn_mfma_f32_16x16x32_bf16(
              af[mt], bfr[nt], acc[mt][nt], 0, 0, 0);
    }
    __syncthreads();
  }
}

// ---------------------------------------------------------------------------
// Kernel 1: QKV projection. A=hidden [4096][2048], W=Wqkv [6144][2048].
// Epilogue: clamp +-8, scatter to q/k/v [32 bh][2048 s][128 d] bf16.
// ---------------------------------------------------------------------------
template <typename TA, typename TB>
__global__ __launch_bounds__(256) void qkv_gemm(
    const TA* __restrict__ A,
    const TB* __restrict__ W,
    __hip_bfloat16* __restrict__ qb,
    __hip_bfloat16* __restrict__ kb,
    __hip_bfloat16* __restrict__ vb)
{
  __shared__ __align__(16) __hip_bfloat16 As[128 * 64];
  __shared__ __align__(16) __hip_bfloat16 Bs[128 * 64];
  const f32x4 z4 = {0.f, 0.f, 0.f, 0.f};
  f32x4 acc[4][4];
  #pragma unroll
  for (int mt = 0; mt < 4; ++mt)
    #pragma unroll
    for (int nt = 0; nt < 4; ++nt) acc[mt][nt] = z4;

  const int K = 2048;
  const int n0 = blockIdx.x * 128, m0 = blockIdx.y * 128;
  gemm_bt_loop(A, W, K, m0, n0, As, Bs, acc);

  const int t = threadIdx.x;
  const int w = t >> 6, lane = t & 63;
  const int wm = (w >> 1) * 64, wn = (w & 1) * 64;
  const int l16 = lane & 15, quad = lane >> 4;
  __hip_bfloat16* bufs[3] = {qb, kb, vb};
  #pragma unroll
  for (int nt = 0; nt < 4; ++nt) {
    int gn = n0 + wn + nt * 16 + l16;
    int which = gn >> 11;          // 0=q 1=k 2=v
    int hc = gn & 2047;
    int head = hc >> 7, d = hc & 127;
    __hip_bfloat16* dst = bufs[which];
    #pragma unroll
    for (int mt = 0; mt < 4; ++mt) {
      #pragma unroll
      for (int r = 0; r < 4; ++r) {
        int gm = m0 + wm + mt * 16 + quad * 4 + r;
        int bb = gm >> 11, s = gm & 2047;
        float val = acc[mt][nt][r];
        val = fminf(8.f, fmaxf(-8.f, val));
        dst[(((int64_t)(bb * 16 + head) * 2048 + s) << 7) + d] =
            __float2bfloat16(val);
      }
    }
  }
}

// ---------------------------------------------------------------------------
// Kernel 2: V transpose per head: V [bh][2048 s][128 d] -> Vt [bh][128 d][2048 s]
// ---------------------------------------------------------------------------
__global__ __launch_bounds__(256) void transpose_v(
    const __hip_bfloat16* __restrict__ V,
    __hip_bfloat16* __restrict__ Vt)
{
  __shared__ __hip_bfloat16 tile[64][68];
  const int bh = blockIdx.z;
  const int s0 = blockIdx.x * 64;
  const int d0 = blockIdx.y * 64;
  const int t = threadIdx.x;
  const int c = t & 63, rq = t >> 6;
  const __hip_bfloat16* Vp = V + (int64_t)bh * 2048 * 128;
  #pragma unroll
  for (int j = 0; j < 16; ++j) {
    int r = rq * 16 + j;
    tile[r][c] = Vp[(int64_t)(s0 + r) * 128 + d0 + c];
  }
  __syncthreads();
  __hip_bfloat16* Vo = Vt + (int64_t)bh * 128 * 2048;
  #pragma unroll
  for (int j = 0; j < 16; ++j) {
    int dd = rq * 16 + j;
    Vo[(int64_t)(d0 + dd) * 2048 + s0 + c] = tile[c][dd];
  }
}

// ---------------------------------------------------------------------------
// Kernel 3: flash attention. One block per (bh, 64-row q-tile).
// 4 waves x 16 q-rows. K tile [128 kpos][128 hd], Vt tile [128 hd][128 kpos],
// bias tile [64 q][128 k] (fp32->bf16 at staging) in LDS; P aliases bias.
// LDS = 80 KB -> 2 blocks/CU; grid 1024 blocks heavy-first for balance.
// ---------------------------------------------------------------------------
__global__ __launch_bounds__(256, 2) void attn_kernel(
    const __hip_bfloat16* __restrict__ Q,
    const __hip_bfloat16* __restrict__ Kg,
    const __hip_bfloat16* __restrict__ Vt,
    const float* __restrict__ bias,
    __hip_bfloat16* __restrict__ ctx)
{
  __shared__ __align__(16) __hip_bfloat16 Ks[128 * 128];   // 32 KB
  __shared__ __align__(16) __hip_bfloat16 Vs[128 * 128];   // 32 KB
  __shared__ __align__(16) __hip_bfloat16 Bs[64 * 128];    // 16 KB bias; reused as P

  const int t = threadIdx.x;
  const int w = t >> 6, lane = t & 63;
  const int l16 = lane & 15, quad = lane >> 4;

  const int bh = blockIdx.y;
  const int h = bh & 15, b = bh >> 4;
  const int qt = 31 - (int)blockIdx.x;       // heavy q-tiles first
  const int q0 = qt * 64;

  // Q fragments: wave w covers q rows [q0 + w*16, +16)
  bf16x8 qf[4];
  {
    const __hip_bfloat16* Qp = Q + ((int64_t)bh * 2048 + q0 + w * 16) * 128;
    #pragma unroll
    for (int ks = 0; ks < 4; ++ks)
      qf[ks] = *(const bf16x8*)(Qp + l16 * 128 + ks * 32 + quad * 8);
  }

  const f32x4 z4 = {0.f, 0.f, 0.f, 0.f};
  f32x4 O[8];
  #pragma unroll
  for (int nt = 0; nt < 8; ++nt) O[nt] = z4;
  float m_r[4], l_r[4];
  #pragma unroll
  for (int r = 0; r < 4; ++r) { m_r[r] = -3.0e38f; l_r[r] = 0.f; }

  const __hip_bfloat16* Kbase = Kg + (int64_t)bh * 2048 * 128;
  const __hip_bfloat16* Vbase = Vt + (int64_t)bh * 128 * 2048;
  const float* Bbase = bias + (int64_t)h * 2048 * 2048;

  const int ktmax = qt >> 1;
  for (int kt = 0; kt <= ktmax; ++kt) {
    const __hip_bfloat16* Kp = Kbase + (int64_t)kt * 128 * 128;
    const __hip_bfloat16* Vp = Vbase + kt * 128;
    // stage K, V, bias in one burst of 16B loads (issued together)
    #pragma unroll
    for (int i = 0; i < 8; ++i) {
      int idx = i * 256 + t;        // 128 rows x 16 chunks
      int row = idx >> 4, ch = idx & 15;
      int sw = (ch ^ (row & 15)) * 8;
      *(bf16x8*)(Ks + row * 128 + sw) =
          *(const bf16x8*)(Kp + row * 128 + ch * 8);
      *(bf16x8*)(Vs + row * 128 + sw) =
          *(const bf16x8*)(Vp + (int64_t)row * 2048 + ch * 8);
    }
    #pragma unroll
    for (int i = 0; i < 4; ++i) {
      int idx = i * 256 + t;        // 64 rows x 16 chunks
      int brow = idx >> 4, ch = idx & 15;
      int sw = (ch ^ (brow & 15)) * 8;
      *(bf16x8*)(Bs + brow * 128 + sw) =
          load8_cvt(Bbase + (int64_t)(q0 + brow) * 2048 + kt * 128 + ch * 8);
    }
    __syncthreads();

    // S = Q * K^T  (16 q-rows x 128 keys per wave)
    f32x4 S[8];
    #pragma unroll
    for (int nt = 0; nt < 8; ++nt) S[nt] = z4;
    #pragma unroll
    for (int ks = 0; ks < 4; ++ks) {
      bf16x8 kf[8];
      #pragma unroll
      for (int nt = 0; nt < 8; ++nt) {
        int row = nt * 16 + l16;
        int ch = ks * 4 + quad;
        kf[nt] = *(const bf16x8*)(Ks + row * 128 + ((ch ^ (row & 15)) * 8));
      }
      #pragma unroll
      for (int nt = 0; nt < 8; ++nt)
        S[nt] = __builtin_amdgcn_mfma_f32_16x16x32_bf16(
            qf[ks], kf[nt], S[nt], 0, 0, 0);
    }

    // scale + bias (from LDS) + causal mask; C layout row=quad*4+r, col=l16
    const bool diag = (kt == ktmax);
    #pragma unroll
    for (int r = 0; r < 4; ++r) {
      int trow = w * 16 + quad * 4 + r;     // tile-local q row 0..63
      int gq = q0 + trow;
      #pragma unroll
      for (int nt = 0; nt < 8; ++nt) {
        int col = nt * 16 + l16;
        float bv = __bfloat162float(
            Bs[trow * 128 + (((col >> 3) ^ (trow & 15)) << 3) + (col & 7)]);
        float sv = S[nt][r] * SOFTMAX_SCALE + bv;
        if (diag && (kt * 128 + col > gq)) sv = -3.0e38f;
        S[nt][r] = sv;
      }
    }

    // online softmax: row stats across the 16 lanes of l16
    #pragma unroll
    for (int r = 0; r < 4; ++r) {
      float rm = S[0][r];
      #pragma unroll
      for (int nt = 1; nt < 8; ++nt) rm = fmaxf(rm, S[nt][r]);
      rm = fmaxf(rm, __shfl_xor(rm, 1, 64));
      rm = fmaxf(rm, __shfl_xor(rm, 2, 64));
      rm = fmaxf(rm, __shfl_xor(rm, 4, 64));
      rm = fmaxf(rm, __shfl_xor(rm, 8, 64));
      float mo = m_r[r];
      float mn = fmaxf(mo, rm);
      float alpha = exp2f((mo - mn) * LOG2E);
      float rs = 0.f;
      #pragma unroll
      for (int nt = 0; nt < 8; ++nt) {
        float pv = exp2f((S[nt][r] - mn) * LOG2E);
        S[nt][r] = pv;
        rs += pv;
      }
      rs += __shfl_xor(rs, 1, 64);
      rs += __shfl_xor(rs, 2, 64);
      rs += __shfl_xor(rs, 4, 64);
      rs += __shfl_xor(rs, 8, 64);
      m_r[r] = mn;
      l_r[r] = l_r[r] * alpha + rs;
      #pragma unroll
      for (int nt = 0; nt < 8; ++nt) O[nt][r] *= alpha;
    }
    __syncthreads();    // all bias/Ks reads done before P overwrites Bs

    // P (bf16) -> Bs, [64 qrow][128 kpos], same swizzle
    #pragma unroll
    for (int r = 0; r < 4; ++r) {
      int trow = w * 16 + quad * 4 + r;
      #pragma unroll
      for (int nt = 0; nt < 8; ++nt) {
        int col = nt * 16 + l16;
        Bs[trow * 128 + (((col >> 3) ^ (trow & 15)) << 3) + (col & 7)] =
            __float2bfloat16(S[nt][r]);
      }
    }
    __syncthreads();

    // O += P * V : A = P[qrow][kpos], B = Vs[hd][kpos]
    #pragma unroll
    for (int ksp = 0; ksp < 4; ++ksp) {
      int ch = ksp * 4 + quad;
      int prow = w * 16 + l16;
      bf16x8 pf = *(const bf16x8*)(Bs + prow * 128 + ((ch ^ (prow & 15)) * 8));
      bf16x8 vf[8];
      #pragma unroll
      for (int nt = 0; nt < 8; ++nt) {
        int row = nt * 16 + l16;
        vf[nt] = *(const bf16x8*)(Vs + row * 128 + ((ch ^ (row & 15)) * 8));
      }
      #pragma unroll
      for (int nt = 0; nt < 8; ++nt)
        O[nt] = __builtin_amdgcn_mfma_f32_16x16x32_bf16(
            pf, vf[nt], O[nt], 0, 0, 0);
    }
    __syncthreads();    // all P/Vs reads done before next tile staging
  }

  // epilogue: ctx[b*2048 + q][h*128 + d] = O / l   (bf16)
  #pragma unroll
  for (int r = 0; r < 4; ++r) {
    int trow = w * 16 + quad * 4 + r;
    int gm = b * 2048 + q0 + trow;
    float inv = 1.f / l_r[r];
    __hip_bfloat16* crow = ctx + (int64_t)gm * 2048 + h * 128;
    #pragma unroll
    for (int nt = 0; nt < 8; ++nt)
      crow[nt * 16 + l16] = __float2bfloat16(O[nt][r] * inv);
  }
}

// ---------------------------------------------------------------------------
// Kernel 4: output projection. A=ctx bf16 [4096][2048], W=Wout [2048][2048].
// Output fp32.
// ---------------------------------------------------------------------------
template <typename TB>
__global__ __launch_bounds__(256) void out_gemm(
    const __hip_bfloat16* __restrict__ A,
    const TB* __restrict__ W,
    float* __restrict__ out)
{
  __shared__ __align__(16) __hip_bfloat16 As[128 * 64];
  __shared__ __align__(16) __hip_bfloat16 Bs[128 * 64];
  const f32x4 z4 = {0.f, 0.f, 0.f, 0.f};
  f32x4 acc[4][4];
  #pragma unroll
  for (int mt = 0; mt < 4; ++mt)
    #pragma unroll
    for (int nt = 0; nt < 4; ++nt) acc[mt][nt] = z4;

  const int K = 2048;
  const int n0 = blockIdx.x * 128, m0 = blockIdx.y * 128;
  gemm_bt_loop(A, W, K, m0, n0, As, Bs, acc);

  const int t = threadIdx.x;
  const int w = t >> 6, lane = t & 63;
  const int wm = (w >> 1) * 64, wn = (w & 1) * 64;
  const int l16 = lane & 15, quad = lane >> 4;
  #pragma unroll
  for (int mt = 0; mt < 4; ++mt) {
    #pragma unroll
    for (int r = 0; r < 4; ++r) {
      int gm = m0 + wm + mt * 16 + quad * 4 + r;
      #pragma unroll
      for (int nt = 0; nt < 4; ++nt) {
        int gn = n0 + wn + nt * 16 + l16;
        out[(int64_t)gm * 2048 + gn] = acc[mt][nt][r];
      }
    }
  }
}

// ---------------------------------------------------------------------------
extern "C" void kernel_launch(void* const* d_in, const int* in_sizes, int n_in,
                              void* d_out, int out_size, void* d_ws, size_t ws_size,
                              hipStream_t stream) {
  const float* hs   = (const float*)d_in[0];
  const float* bias = (const float*)d_in[1];
  // d_in[2] = attention_mask: pure causal, applied analytically; never read.
  const float* Wqkv = (const float*)d_in[3];
  const float* Wout = (const float*)d_in[4];
  float* out = (float*)d_out;

  __hip_bfloat16* ws = (__hip_bfloat16*)d_ws;
  const size_t SEG = (size_t)32 * 2048 * 128;   // 8,388,608 elements (16 MB)
  __hip_bfloat16* q   = ws;
  __hip_bfloat16* k   = ws + SEG;
  __hip_bfloat16* v   = ws + 2 * SEG;
  __hip_bfloat16* vt  = ws + 3 * SEG;
  __hip_bfloat16* ctx = ws + 2 * SEG;           // aliases v (dead after transpose)

  const size_t NW_QKV = (size_t)6144 * 2048;    // 12,582,912
  const size_t NW_OUT = (size_t)2048 * 2048;    //  4,194,304
  const size_t need_bytes = (4 * SEG + NW_QKV + SEG) * sizeof(__hip_bfloat16);

  if (ws_size >= need_bytes) {
    // fast path: pre-convert operands to bf16, halving GEMM staging bytes
    __hip_bfloat16* wqkvb = ws + 4 * SEG;
    __hip_bfloat16* hsb   = wqkvb + NW_QKV;
    __hip_bfloat16* woutb = wqkvb;              // aliases wqkvb (dead after qkv)
    cvt_f32_bf16<<<1024, 256, 0, stream>>>(hs, hsb, (int)(SEG / 8));
    cvt_f32_bf16<<<1024, 256, 0, stream>>>(Wqkv, wqkvb, (int)(NW_QKV / 8));
    qkv_gemm<__hip_bfloat16, __hip_bfloat16>
        <<<dim3(48, 32), 256, 0, stream>>>(hsb, wqkvb, q, k, v);
    transpose_v<<<dim3(32, 2, 32), 256, 0, stream>>>(v, vt);
    cvt_f32_bf16<<<1024, 256, 0, stream>>>(Wout, woutb, (int)(NW_OUT / 8));
    attn_kernel<<<dim3(32, 32), 256, 0, stream>>>(q, k, vt, bias, ctx);
    out_gemm<__hip_bfloat16><<<dim3(16, 32), 256, 0, stream>>>(ctx, woutb, out);
  } else {
    // fallback: fp32-direct staging (round-2 proven path)
    qkv_gemm<float, float><<<dim3(48, 32), 256, 0, stream>>>(hs, Wqkv, q, k, v);
    transpose_v<<<dim3(32, 2, 32), 256, 0, stream>>>(v, vt);
    attn_kernel<<<dim3(32, 32), 256, 0, stream>>>(q, k, vt, bias, ctx);
    out_gemm<float><<<dim3(16, 32), 256, 0, stream>>>(ctx, Wout, out);
  }
}